// Round 1
// baseline (1301.019 us; speedup 1.0000x reference)
//
#include <hip/hip_runtime.h>

#define SLOPE_ATT 0.2f
#define SLOPE_ACT 0.01f

__device__ __forceinline__ unsigned fkey(float f) {
  unsigned b = __float_as_uint(f);
  return (b & 0x80000000u) ? ~b : (b | 0x80000000u);
}
__device__ __forceinline__ float funkey(unsigned k) {
  unsigned b = (k & 0x80000000u) ? (k ^ 0x80000000u) : ~k;
  return __uint_as_float(b);
}

// Fused GEMM (h = x @ W) + per-node attention dots a_src/a_dst.
// Block = 128 threads (one output column each), 8 nodes per block.
template<int FIN, int H, int C>
__global__ __launch_bounds__(128)
void gemm_att_kernel(const float* __restrict__ x, const float* __restrict__ W,
                     const float* __restrict__ att_s, const float* __restrict__ att_d,
                     float* __restrict__ hout, float* __restrict__ a_src,
                     float* __restrict__ a_dst, int N)
{
  constexpr int HC = H * C;      // always 128 here
  constexpr int NODES = 8;
  __shared__ float xs[NODES][FIN];
  __shared__ float red[2][NODES][2];
  const int tid = threadIdx.x;
  const int node0 = blockIdx.x * NODES;

  for (int i = 0; i < NODES; ++i) {
    int n = node0 + i;
    const float* xr = x + (size_t)n * FIN;
    for (int k = tid; k < FIN; k += 128)
      xs[i][k] = (n < N) ? xr[k] : 0.f;
  }
  __syncthreads();

  float acc[NODES];
#pragma unroll
  for (int i = 0; i < NODES; ++i) acc[i] = 0.f;

  for (int k = 0; k < FIN; k += 4) {
    float w0 = W[(size_t)(k+0)*HC + tid];
    float w1 = W[(size_t)(k+1)*HC + tid];
    float w2 = W[(size_t)(k+2)*HC + tid];
    float w3 = W[(size_t)(k+3)*HC + tid];
#pragma unroll
    for (int i = 0; i < NODES; ++i) {
      float4 xv = *reinterpret_cast<const float4*>(&xs[i][k]);
      acc[i] += xv.x*w0 + xv.y*w1 + xv.z*w2 + xv.w*w3;
    }
  }

  const float as_w = att_s[tid];
  const float ad_w = att_d[tid];
#pragma unroll
  for (int i = 0; i < NODES; ++i) {
    int n = node0 + i;
    float v = acc[i];
    if (n < N) hout[(size_t)n*HC + tid] = v;
    float vs = v * as_w;
    float vd = v * ad_w;
    if constexpr (C == 32) {
#pragma unroll
      for (int off = 16; off >= 1; off >>= 1) {
        vs += __shfl_xor(vs, off);
        vd += __shfl_xor(vd, off);
      }
      if ((tid & 31) == 0 && n < N) {
        a_src[(size_t)n*H + (tid>>5)] = vs;
        a_dst[(size_t)n*H + (tid>>5)] = vd;
      }
    } else {  // C == 128: block-wide reduce
#pragma unroll
      for (int off = 32; off >= 1; off >>= 1) {
        vs += __shfl_xor(vs, off);
        vd += __shfl_xor(vd, off);
      }
      if ((tid & 63) == 0) { red[0][i][tid>>6] = vs; red[1][i][tid>>6] = vd; }
    }
  }
  if constexpr (C == 128) {
    __syncthreads();
    if (tid < NODES) {
      int n = node0 + tid;
      if (n < N) {
        a_src[n] = red[0][tid][0] + red[0][tid][1];
        a_dst[n] = red[1][tid][0] + red[1][tid][1];
      }
    }
  }
}

template<int H>
__global__ __launch_bounds__(256)
void edge_max_kernel(const int* __restrict__ ei, int E, int N,
                     const float* __restrict__ a_src,
                     const float* __restrict__ a_dst,
                     unsigned* __restrict__ m)
{
  int idx = blockIdx.x * blockDim.x + threadIdx.x;
  int EE = E + N;
  if (idx >= EE) return;
  int s, d;
  if (idx < E) { s = ei[idx]; d = ei[E + idx]; } else { s = d = idx - E; }
#pragma unroll
  for (int h = 0; h < H; ++h) {
    float e = a_src[(size_t)s*H + h] + a_dst[(size_t)d*H + h];
    e = (e >= 0.f) ? e : SLOPE_ATT * e;
    atomicMax(&m[(size_t)d*H + h], fkey(e));
  }
}

template<int H>
__global__ __launch_bounds__(256)
void edge_expsum_kernel(const int* __restrict__ ei, int E, int N,
                        const float* __restrict__ a_src,
                        const float* __restrict__ a_dst,
                        const unsigned* __restrict__ m,
                        float* __restrict__ ex, float* __restrict__ Z)
{
  int idx = blockIdx.x * blockDim.x + threadIdx.x;
  int EE = E + N;
  if (idx >= EE) return;
  int s, d;
  if (idx < E) { s = ei[idx]; d = ei[E + idx]; } else { s = d = idx - E; }
#pragma unroll
  for (int h = 0; h < H; ++h) {
    float e = a_src[(size_t)s*H + h] + a_dst[(size_t)d*H + h];
    e = (e >= 0.f) ? e : SLOPE_ATT * e;
    float mv = funkey(m[(size_t)d*H + h]);
    float xv = __expf(e - mv);
    ex[(size_t)idx*H + h] = xv;
    atomicAdd(&Z[(size_t)d*H + h], xv);
  }
}

// One 128-thread half-block per edge; 2 edges per 256-thread block.
template<int H>
__global__ __launch_bounds__(256)
void message_kernel(const int* __restrict__ ei, int E, int N,
                    const float* __restrict__ hfeat,
                    const float* __restrict__ ex, const float* __restrict__ Z,
                    float* __restrict__ out)
{
  int e = blockIdx.x * 2 + (threadIdx.x >> 7);
  int tid = threadIdx.x & 127;
  int EE = E + N;
  if (e >= EE) return;
  int s, d;
  if (e < E) { s = ei[e]; d = ei[E + e]; } else { s = d = e - E; }
  int head = (tid * H) >> 7;
  float alpha = ex[(size_t)e*H + head] / (Z[(size_t)d*H + head] + 1e-16f);
  atomicAdd(&out[(size_t)d*128 + tid], alpha * hfeat[(size_t)s*128 + tid]);
}

__global__ __launch_bounds__(256)
void finalize_kernel(float* __restrict__ io, const float* __restrict__ bias, int n4)
{
  int idx = blockIdx.x * blockDim.x + threadIdx.x;
  if (idx >= n4) return;
  float4 v = reinterpret_cast<float4*>(io)[idx];
  float4 b = reinterpret_cast<const float4*>(bias)[idx & 31];
  v.x += b.x; v.y += b.y; v.z += b.z; v.w += b.w;
  v.x = v.x >= 0.f ? v.x : SLOPE_ACT * v.x;
  v.y = v.y >= 0.f ? v.y : SLOPE_ACT * v.y;
  v.z = v.z >= 0.f ? v.z : SLOPE_ACT * v.z;
  v.w = v.w >= 0.f ? v.w : SLOPE_ACT * v.w;
  reinterpret_cast<float4*>(io)[idx] = v;
}

extern "C" void kernel_launch(void* const* d_in, const int* in_sizes, int n_in,
                              void* d_out, int out_size, void* d_ws, size_t ws_size,
                              hipStream_t stream)
{
  const float* x   = (const float*)d_in[0];
  const int*   ei  = (const int*)d_in[1];
  const float* W1  = (const float*)d_in[2];
  const float* as1 = (const float*)d_in[3];
  const float* ad1 = (const float*)d_in[4];
  const float* b1  = (const float*)d_in[5];
  const float* W2  = (const float*)d_in[6];
  const float* as2 = (const float*)d_in[7];
  const float* ad2 = (const float*)d_in[8];
  const float* b2  = (const float*)d_in[9];
  float* out = (float*)d_out;

  const int N  = in_sizes[0] / 256;
  const int E  = in_sizes[1] / 2;
  const int EE = E + N;

  float* ws = (float*)d_ws;
  size_t o = 0;
  float* h    = ws + o; o += (size_t)N * 128;   // h1, reused as h2
  float* acc  = ws + o; o += (size_t)N * 128;   // layer1 accum -> act1
  float* asv  = ws + o; o += (size_t)N * 4;
  float* adv  = ws + o; o += (size_t)N * 4;
  unsigned* m = (unsigned*)(ws + o); o += (size_t)N * 4;
  float* Z    = ws + o; o += (size_t)N * 4;
  float* ex   = ws + o; o += (size_t)EE * 4;

  const int egrid = (EE + 255) / 256;
  const int fgrid = ((N * 128 / 4) + 255) / 256;

  // ---------------- layer 1 (H=4, C=32, FIN=256) ----------------
  hipMemsetAsync(acc, 0, (size_t)N * 128 * sizeof(float), stream);
  hipMemsetAsync(m,   0, (size_t)N * 4 * sizeof(unsigned), stream);
  hipMemsetAsync(Z,   0, (size_t)N * 4 * sizeof(float), stream);

  gemm_att_kernel<256,4,32><<<(N + 7) / 8, 128, 0, stream>>>(x, W1, as1, ad1, h, asv, adv, N);
  edge_max_kernel<4><<<egrid, 256, 0, stream>>>(ei, E, N, asv, adv, m);
  edge_expsum_kernel<4><<<egrid, 256, 0, stream>>>(ei, E, N, asv, adv, m, ex, Z);
  message_kernel<4><<<(EE + 1) / 2, 256, 0, stream>>>(ei, E, N, h, ex, Z, acc);
  finalize_kernel<<<fgrid, 256, 0, stream>>>(acc, b1, N * 128 / 4);

  // ---------------- layer 2 (H=1, C=128, FIN=128) ----------------
  hipMemsetAsync(out, 0, (size_t)N * 128 * sizeof(float), stream);
  hipMemsetAsync(m,   0, (size_t)N * sizeof(unsigned), stream);
  hipMemsetAsync(Z,   0, (size_t)N * sizeof(float), stream);

  gemm_att_kernel<128,1,128><<<(N + 7) / 8, 128, 0, stream>>>(acc, W2, as2, ad2, h, asv, adv, N);
  edge_max_kernel<1><<<egrid, 256, 0, stream>>>(ei, E, N, asv, adv, m);
  edge_expsum_kernel<1><<<egrid, 256, 0, stream>>>(ei, E, N, asv, adv, m, ex, Z);
  message_kernel<1><<<(EE + 1) / 2, 256, 0, stream>>>(ei, E, N, h, ex, Z, out);
  finalize_kernel<<<fgrid, 256, 0, stream>>>(out, b2, N * 128 / 4);
}

// Round 2
// 544.402 us; speedup vs baseline: 2.3898x; 2.3898x over previous
//
#include <hip/hip_runtime.h>

#define SLOPE_ATT 0.2f
#define SLOPE_ACT 0.01f

// ---------------------------------------------------------------------------
// Fused GEMM (h = x @ W) + per-node attention dots a_src/a_dst. Unchanged R1.
// Block = 128 threads (one output column each), 8 nodes per block.
template<int FIN, int H, int C>
__global__ __launch_bounds__(128)
void gemm_att_kernel(const float* __restrict__ x, const float* __restrict__ W,
                     const float* __restrict__ att_s, const float* __restrict__ att_d,
                     float* __restrict__ hout, float* __restrict__ a_src,
                     float* __restrict__ a_dst, int N)
{
  constexpr int HC = H * C;      // always 128 here
  constexpr int NODES = 8;
  __shared__ float xs[NODES][FIN];
  __shared__ float red[2][NODES][2];
  const int tid = threadIdx.x;
  const int node0 = blockIdx.x * NODES;

  for (int i = 0; i < NODES; ++i) {
    int n = node0 + i;
    const float* xr = x + (size_t)n * FIN;
    for (int k = tid; k < FIN; k += 128)
      xs[i][k] = (n < N) ? xr[k] : 0.f;
  }
  __syncthreads();

  float acc[NODES];
#pragma unroll
  for (int i = 0; i < NODES; ++i) acc[i] = 0.f;

  for (int k = 0; k < FIN; k += 4) {
    float w0 = W[(size_t)(k+0)*HC + tid];
    float w1 = W[(size_t)(k+1)*HC + tid];
    float w2 = W[(size_t)(k+2)*HC + tid];
    float w3 = W[(size_t)(k+3)*HC + tid];
#pragma unroll
    for (int i = 0; i < NODES; ++i) {
      float4 xv = *reinterpret_cast<const float4*>(&xs[i][k]);
      acc[i] += xv.x*w0 + xv.y*w1 + xv.z*w2 + xv.w*w3;
    }
  }

  const float as_w = att_s[tid];
  const float ad_w = att_d[tid];
#pragma unroll
  for (int i = 0; i < NODES; ++i) {
    int n = node0 + i;
    float v = acc[i];
    if (n < N) hout[(size_t)n*HC + tid] = v;
    float vs = v * as_w;
    float vd = v * ad_w;
    if constexpr (C == 32) {
#pragma unroll
      for (int off = 16; off >= 1; off >>= 1) {
        vs += __shfl_xor(vs, off);
        vd += __shfl_xor(vd, off);
      }
      if ((tid & 31) == 0 && n < N) {
        a_src[(size_t)n*H + (tid>>5)] = vs;
        a_dst[(size_t)n*H + (tid>>5)] = vd;
      }
    } else {  // C == 128: block-wide reduce
#pragma unroll
      for (int off = 32; off >= 1; off >>= 1) {
        vs += __shfl_xor(vs, off);
        vd += __shfl_xor(vd, off);
      }
      if ((tid & 63) == 0) { red[0][i][tid>>6] = vs; red[1][i][tid>>6] = vd; }
    }
  }
  if constexpr (C == 128) {
    __syncthreads();
    if (tid < NODES) {
      int n = node0 + tid;
      if (n < N) {
        a_src[n] = red[0][tid][0] + red[0][tid][1];
        a_dst[n] = red[1][tid][0] + red[1][tid][1];
      }
    }
  }
}

// ---------------------------------------------------------------------------
// CSR construction (dst-sorted). Self-loops appended as edges [E, E+N).
__global__ __launch_bounds__(256)
void hist_kernel(const int* __restrict__ ei, int E, int N, unsigned* __restrict__ deg)
{
  int idx = blockIdx.x * blockDim.x + threadIdx.x;
  int EE = E + N;
  if (idx >= EE) return;
  int d = (idx < E) ? ei[E + idx] : (idx - E);
  atomicAdd(&deg[d], 1u);
}

// Single-block exclusive scan over deg[N] -> row_start, cursor.
__global__ __launch_bounds__(1024)
void scan_kernel(const unsigned* __restrict__ deg, unsigned* __restrict__ row_start,
                 unsigned* __restrict__ cursor, int N)
{
  __shared__ unsigned sums[1024];
  const int t = threadIdx.x;
  const int C = (N + 1023) / 1024;
  const int lo = t * C;
  const int hi = min(lo + C, N);
  unsigned s = 0;
  for (int i = lo; i < hi; ++i) s += deg[i];
  sums[t] = s;
  __syncthreads();
  // Hillis-Steele inclusive scan
  for (int off = 1; off < 1024; off <<= 1) {
    unsigned v = (t >= off) ? sums[t - off] : 0u;
    __syncthreads();
    sums[t] += v;
    __syncthreads();
  }
  unsigned run = (t > 0) ? sums[t - 1] : 0u;
  for (int i = lo; i < hi; ++i) {
    row_start[i] = run;
    cursor[i] = run;
    run += deg[i];
  }
}

__global__ __launch_bounds__(256)
void scatter_kernel(const int* __restrict__ ei, int E, int N,
                    unsigned* __restrict__ cursor, unsigned* __restrict__ csr_src)
{
  int idx = blockIdx.x * blockDim.x + threadIdx.x;
  int EE = E + N;
  if (idx >= EE) return;
  int s, d;
  if (idx < E) { s = ei[idx]; d = ei[E + idx]; } else { s = d = idx - E; }
  unsigned pos = atomicAdd(&cursor[d], 1u);
  csr_src[pos] = (unsigned)s;
}

// ---------------------------------------------------------------------------
// Fused per-node aggregation: online softmax over incoming edges + weighted
// sum of h[src] + bias + leakyReLU. One 64-lane wave per dst node, each lane
// owns 2 contiguous features (float2).
template<int H>
__global__ __launch_bounds__(256)
void aggregate_kernel(const unsigned* __restrict__ row_start,
                      const unsigned* __restrict__ deg,
                      const unsigned* __restrict__ csr_src,
                      const float* __restrict__ h,
                      const float* __restrict__ a_src,
                      const float* __restrict__ a_dst,
                      const float* __restrict__ bias,
                      float* __restrict__ out, int N)
{
  const int n = blockIdx.x * 4 + (threadIdx.x >> 6);
  if (n >= N) return;
  const int l = threadIdx.x & 63;
  const int hd = (H == 4) ? (l >> 4) : 0;   // feature 2l -> head (2l)/32

  const float adn = a_dst[(size_t)n * H + hd];
  const unsigned beg = row_start[n];
  const unsigned cnt = deg[n];              // >= 1 (self loop)
  const float2* __restrict__ h2 = (const float2*)h;

  float m = -1e30f, Z = 0.f, ax = 0.f, ay = 0.f;
  for (unsigned i = 0; i < cnt; ++i) {
    unsigned s = csr_src[beg + i];
    float a = a_src[(size_t)s * H + hd];
    float e = a + adn;
    e = (e >= 0.f) ? e : SLOPE_ATT * e;
    float mn = fmaxf(m, e);
    float sc = __expf(m - mn);              // exp(-1e30) underflows to 0
    float w  = __expf(e - mn);
    float2 hv = h2[(size_t)s * 64 + l];
    Z  = Z  * sc + w;
    ax = ax * sc + w * hv.x;
    ay = ay * sc + w * hv.y;
    m = mn;
  }
  const float inv = 1.f / (Z + 1e-16f);
  float2 b = ((const float2*)bias)[l];
  float ox = ax * inv + b.x;
  float oy = ay * inv + b.y;
  ox = (ox >= 0.f) ? ox : SLOPE_ACT * ox;
  oy = (oy >= 0.f) ? oy : SLOPE_ACT * oy;
  ((float2*)out)[(size_t)n * 64 + l] = make_float2(ox, oy);
}

// ---------------------------------------------------------------------------
extern "C" void kernel_launch(void* const* d_in, const int* in_sizes, int n_in,
                              void* d_out, int out_size, void* d_ws, size_t ws_size,
                              hipStream_t stream)
{
  const float* x   = (const float*)d_in[0];
  const int*   ei  = (const int*)d_in[1];
  const float* W1  = (const float*)d_in[2];
  const float* as1 = (const float*)d_in[3];
  const float* ad1 = (const float*)d_in[4];
  const float* b1  = (const float*)d_in[5];
  const float* W2  = (const float*)d_in[6];
  const float* as2 = (const float*)d_in[7];
  const float* ad2 = (const float*)d_in[8];
  const float* b2  = (const float*)d_in[9];
  float* out = (float*)d_out;

  const int N  = in_sizes[0] / 256;
  const int E  = in_sizes[1] / 2;
  const int EE = E + N;

  float* ws = (float*)d_ws;
  size_t o = 0;
  float* h    = ws + o; o += (size_t)N * 128;   // gemm output, reused per layer
  float* act1 = ws + o; o += (size_t)N * 128;   // layer-1 activations
  float* asv  = ws + o; o += (size_t)N * 4;
  float* adv  = ws + o; o += (size_t)N * 4;
  unsigned* deg       = (unsigned*)(ws + o); o += (size_t)N;
  unsigned* row_start = (unsigned*)(ws + o); o += (size_t)N;
  unsigned* cursor    = (unsigned*)(ws + o); o += (size_t)N;
  unsigned* csr_src   = (unsigned*)(ws + o); o += (size_t)EE;

  const int egrid = (EE + 255) / 256;
  const int ngrid = (N + 3) / 4;

  // ---- CSR build (graph is identical for both layers) ----
  hipMemsetAsync(deg, 0, (size_t)N * sizeof(unsigned), stream);
  hist_kernel<<<egrid, 256, 0, stream>>>(ei, E, N, deg);
  scan_kernel<<<1, 1024, 0, stream>>>(deg, row_start, cursor, N);
  scatter_kernel<<<egrid, 256, 0, stream>>>(ei, E, N, cursor, csr_src);

  // ---- layer 1 (H=4, C=32, FIN=256) ----
  gemm_att_kernel<256,4,32><<<(N + 7) / 8, 128, 0, stream>>>(x, W1, as1, ad1, h, asv, adv, N);
  aggregate_kernel<4><<<ngrid, 256, 0, stream>>>(row_start, deg, csr_src, h, asv, adv, b1, act1, N);

  // ---- layer 2 (H=1, C=128, FIN=128) ----
  gemm_att_kernel<128,1,128><<<(N + 7) / 8, 128, 0, stream>>>(act1, W2, as2, ad2, h, asv, adv, N);
  aggregate_kernel<1><<<ngrid, 256, 0, stream>>>(row_start, deg, csr_src, h, asv, adv, b2, out, N);
}

// Round 3
// 340.257 us; speedup vs baseline: 3.8236x; 1.6000x over previous
//
#include <hip/hip_runtime.h>

#define SLOPE_ATT 0.2f
#define SLOPE_ACT 0.01f

// ---------------------------------------------------------------------------
// Register-blocked fp32 GEMM (h = A @ B), A:[M][K], B:[K][128], fused att dots.
// Block 256 thr = 4 waves; C-tile 64 rows x 128 cols; per-thread 4x8.
// tx = tid&15 (col octet), ty = tid>>4 (row quad).
template<int K, int H>
__global__ __launch_bounds__(256)
void gemm_fused_kernel(const float* __restrict__ A, const float* __restrict__ B,
                       const float* __restrict__ att_s, const float* __restrict__ att_d,
                       float* __restrict__ hout, float* __restrict__ a_src,
                       float* __restrict__ a_dst, int M)
{
  constexpr int BK = 16;
  constexpr int TILES = K / BK;
  __shared__ float As[BK][68];    // [k][row], pad 64->68: reads 4-bank spread
  __shared__ float Bs[BK][192];   // 16 col-chunks of 8 floats at stride 12
  const int tid = threadIdx.x;
  const int tx = tid & 15;
  const int ty = tid >> 4;
  const int m0 = blockIdx.x * 64;

  // staging indices
  const int ar = tid >> 2;            // 0..63 (row)
  const int af = tid & 3;             // float4 idx along k
  const int bk = tid >> 5;            // 0..7 (k row; second pass +8)
  const int bc = tid & 31;            // col float4

  float acc[4][8];
#pragma unroll
  for (int i = 0; i < 4; ++i)
#pragma unroll
    for (int j = 0; j < 8; ++j) acc[i][j] = 0.f;

  const float4 zero4 = make_float4(0.f, 0.f, 0.f, 0.f);
  const int gr = m0 + ar;

  float4 aReg, bReg0, bReg1;
  aReg  = (gr < M) ? *(const float4*)&A[(size_t)gr * K + af * 4] : zero4;
  bReg0 = *(const float4*)&B[(size_t)bk * 128 + bc * 4];
  bReg1 = *(const float4*)&B[(size_t)(bk + 8) * 128 + bc * 4];

  for (int t = 0; t < TILES; ++t) {
    As[af*4+0][ar] = aReg.x;
    As[af*4+1][ar] = aReg.y;
    As[af*4+2][ar] = aReg.z;
    As[af*4+3][ar] = aReg.w;
    *(float4*)&Bs[bk    ][(bc >> 1) * 12 + (bc & 1) * 4] = bReg0;
    *(float4*)&Bs[bk + 8][(bc >> 1) * 12 + (bc & 1) * 4] = bReg1;
    __syncthreads();

    if (t + 1 < TILES) {
      const int kb = (t + 1) * BK;
      aReg  = (gr < M) ? *(const float4*)&A[(size_t)gr * K + kb + af * 4] : zero4;
      bReg0 = *(const float4*)&B[(size_t)(kb + bk) * 128 + bc * 4];
      bReg1 = *(const float4*)&B[(size_t)(kb + bk + 8) * 128 + bc * 4];
    }

#pragma unroll
    for (int k = 0; k < BK; ++k) {
      float4 av = *(const float4*)&As[k][ty * 4];
      float4 b0 = *(const float4*)&Bs[k][tx * 12];
      float4 b1 = *(const float4*)&Bs[k][tx * 12 + 4];
      float arr[4] = {av.x, av.y, av.z, av.w};
      float brr[8] = {b0.x, b0.y, b0.z, b0.w, b1.x, b1.y, b1.z, b1.w};
#pragma unroll
      for (int i = 0; i < 4; ++i)
#pragma unroll
        for (int j = 0; j < 8; ++j) acc[i][j] += arr[i] * brr[j];
    }
    __syncthreads();
  }

  // epilogue: store h + fused attention dots
  const float4 s0v = *(const float4*)&att_s[tx * 8];
  const float4 s1v = *(const float4*)&att_s[tx * 8 + 4];
  const float4 d0v = *(const float4*)&att_d[tx * 8];
  const float4 d1v = *(const float4*)&att_d[tx * 8 + 4];
#pragma unroll
  for (int i = 0; i < 4; ++i) {
    const int r = m0 + ty * 4 + i;
    const bool ok = r < M;
    if (ok) {
      *(float4*)&hout[(size_t)r * 128 + tx * 8]     = make_float4(acc[i][0], acc[i][1], acc[i][2], acc[i][3]);
      *(float4*)&hout[(size_t)r * 128 + tx * 8 + 4] = make_float4(acc[i][4], acc[i][5], acc[i][6], acc[i][7]);
    }
    float sp = acc[i][0]*s0v.x + acc[i][1]*s0v.y + acc[i][2]*s0v.z + acc[i][3]*s0v.w
             + acc[i][4]*s1v.x + acc[i][5]*s1v.y + acc[i][6]*s1v.z + acc[i][7]*s1v.w;
    float dp = acc[i][0]*d0v.x + acc[i][1]*d0v.y + acc[i][2]*d0v.z + acc[i][3]*d0v.w
             + acc[i][4]*d1v.x + acc[i][5]*d1v.y + acc[i][6]*d1v.z + acc[i][7]*d1v.w;
    if (H == 4) {
      sp += __shfl_xor(sp, 1); sp += __shfl_xor(sp, 2);
      dp += __shfl_xor(dp, 1); dp += __shfl_xor(dp, 2);
      if ((tx & 3) == 0 && ok) {
        a_src[(size_t)r * 4 + (tx >> 2)] = sp;
        a_dst[(size_t)r * 4 + (tx >> 2)] = dp;
      }
    } else {
      sp += __shfl_xor(sp, 1); sp += __shfl_xor(sp, 2);
      sp += __shfl_xor(sp, 4); sp += __shfl_xor(sp, 8);
      dp += __shfl_xor(dp, 1); dp += __shfl_xor(dp, 2);
      dp += __shfl_xor(dp, 4); dp += __shfl_xor(dp, 8);
      if (tx == 0 && ok) { a_src[r] = sp; a_dst[r] = dp; }
    }
  }
}

// ---------------------------------------------------------------------------
// CSR construction (dst-sorted). Self-loops appended as edges [E, E+N).
__global__ __launch_bounds__(256)
void hist_kernel(const int* __restrict__ ei, int E, int N, unsigned* __restrict__ deg)
{
  int idx = blockIdx.x * blockDim.x + threadIdx.x;
  int EE = E + N;
  if (idx >= EE) return;
  int d = (idx < E) ? ei[E + idx] : (idx - E);
  atomicAdd(&deg[d], 1u);
}

// Hierarchical scan: 256-block partial sums -> 1-block scan -> 256-block local.
__global__ __launch_bounds__(256)
void partial_sum_kernel(const unsigned* __restrict__ deg, unsigned* __restrict__ bsum,
                        int N, int C)
{
  __shared__ unsigned red[256];
  const int b = blockIdx.x;
  const int lo = b * C;
  const int hi = min(lo + C, N);
  unsigned s = 0;
  for (int i = lo + threadIdx.x; i < hi; i += 256) s += deg[i];
  red[threadIdx.x] = s;
  __syncthreads();
  for (int off = 128; off; off >>= 1) {
    if (threadIdx.x < off) red[threadIdx.x] += red[threadIdx.x + off];
    __syncthreads();
  }
  if (threadIdx.x == 0) bsum[b] = red[0];
}

__global__ __launch_bounds__(256)
void scan_bsum_kernel(const unsigned* __restrict__ bsum, unsigned* __restrict__ boff)
{
  __shared__ unsigned s[256];
  const int t = threadIdx.x;
  s[t] = bsum[t];
  __syncthreads();
  for (int off = 1; off < 256; off <<= 1) {
    unsigned v = (t >= off) ? s[t - off] : 0u;
    __syncthreads();
    s[t] += v;
    __syncthreads();
  }
  boff[t] = s[t] - bsum[t];   // exclusive
}

// C <= 256 assumed (N <= 65536).
__global__ __launch_bounds__(256)
void rowstart_kernel(const unsigned* __restrict__ deg, const unsigned* __restrict__ boff,
                     unsigned* __restrict__ row_start, unsigned* __restrict__ cursor,
                     int N, int C)
{
  __shared__ unsigned s[256];
  const int b = blockIdx.x;
  const int t = threadIdx.x;
  const int i = b * C + t;
  const unsigned d = (t < C && i < N) ? deg[i] : 0u;
  s[t] = d;
  __syncthreads();
  for (int off = 1; off < 256; off <<= 1) {
    unsigned v = (t >= off) ? s[t - off] : 0u;
    __syncthreads();
    s[t] += v;
    __syncthreads();
  }
  if (t < C && i < N) {
    unsigned rs = boff[b] + s[t] - d;
    row_start[i] = rs;
    cursor[i] = rs;
  }
}

__global__ __launch_bounds__(256)
void scatter_kernel(const int* __restrict__ ei, int E, int N,
                    unsigned* __restrict__ cursor, unsigned* __restrict__ csr_src)
{
  int idx = blockIdx.x * blockDim.x + threadIdx.x;
  int EE = E + N;
  if (idx >= EE) return;
  int s, d;
  if (idx < E) { s = ei[idx]; d = ei[E + idx]; } else { s = d = idx - E; }
  unsigned pos = atomicAdd(&cursor[d], 1u);
  csr_src[pos] = (unsigned)s;
}

// ---------------------------------------------------------------------------
// Fused per-node aggregation. Softmax without max-subtraction (shift-invariant;
// e ~ N(0,1) here so exp cannot overflow). One wave per node; lane owns 2 feats.
template<int H>
__global__ __launch_bounds__(256)
void aggregate_kernel(const unsigned* __restrict__ row_start,
                      const unsigned* __restrict__ deg,
                      const unsigned* __restrict__ csr_src,
                      const float* __restrict__ h,
                      const float* __restrict__ a_src,
                      const float* __restrict__ a_dst,
                      const float* __restrict__ bias,
                      float* __restrict__ out, int N)
{
  const int n = blockIdx.x * 4 + (threadIdx.x >> 6);
  if (n >= N) return;
  const int l = threadIdx.x & 63;
  const int hd = (H == 4) ? (l >> 4) : 0;

  const float adn = a_dst[(size_t)n * H + hd];
  const unsigned beg = row_start[n];
  const unsigned cnt = deg[n];              // >= 1 (self loop)
  const float2* __restrict__ h2 = (const float2*)h;

  float Z = 0.f, ax = 0.f, ay = 0.f;
  unsigned i = 0;
  for (; i + 2 <= cnt; i += 2) {
    unsigned s0 = csr_src[beg + i];
    unsigned s1 = csr_src[beg + i + 1];
    float e0 = a_src[(size_t)s0 * H + hd] + adn;
    float e1 = a_src[(size_t)s1 * H + hd] + adn;
    e0 = (e0 >= 0.f) ? e0 : SLOPE_ATT * e0;
    e1 = (e1 >= 0.f) ? e1 : SLOPE_ATT * e1;
    float w0 = __expf(e0);
    float w1 = __expf(e1);
    float2 v0 = h2[(size_t)s0 * 64 + l];
    float2 v1 = h2[(size_t)s1 * 64 + l];
    Z  += w0 + w1;
    ax += w0 * v0.x + w1 * v1.x;
    ay += w0 * v0.y + w1 * v1.y;
  }
  if (i < cnt) {
    unsigned s0 = csr_src[beg + i];
    float e0 = a_src[(size_t)s0 * H + hd] + adn;
    e0 = (e0 >= 0.f) ? e0 : SLOPE_ATT * e0;
    float w0 = __expf(e0);
    float2 v0 = h2[(size_t)s0 * 64 + l];
    Z  += w0;
    ax += w0 * v0.x;
    ay += w0 * v0.y;
  }
  const float inv = 1.f / (Z + 1e-16f);
  float2 b = ((const float2*)bias)[l];
  float ox = ax * inv + b.x;
  float oy = ay * inv + b.y;
  ox = (ox >= 0.f) ? ox : SLOPE_ACT * ox;
  oy = (oy >= 0.f) ? oy : SLOPE_ACT * oy;
  ((float2*)out)[(size_t)n * 64 + l] = make_float2(ox, oy);
}

// ---------------------------------------------------------------------------
extern "C" void kernel_launch(void* const* d_in, const int* in_sizes, int n_in,
                              void* d_out, int out_size, void* d_ws, size_t ws_size,
                              hipStream_t stream)
{
  const float* x   = (const float*)d_in[0];
  const int*   ei  = (const int*)d_in[1];
  const float* W1  = (const float*)d_in[2];
  const float* as1 = (const float*)d_in[3];
  const float* ad1 = (const float*)d_in[4];
  const float* b1  = (const float*)d_in[5];
  const float* W2  = (const float*)d_in[6];
  const float* as2 = (const float*)d_in[7];
  const float* ad2 = (const float*)d_in[8];
  const float* b2  = (const float*)d_in[9];
  float* out = (float*)d_out;

  const int N  = in_sizes[0] / 256;
  const int E  = in_sizes[1] / 2;
  const int EE = E + N;
  const int C  = (N + 255) / 256;   // <= 256 for N <= 65536

  float* ws = (float*)d_ws;
  size_t o = 0;
  float* h    = ws + o; o += (size_t)N * 128;   // gemm output, reused per layer
  float* act1 = ws + o; o += (size_t)N * 128;   // layer-1 activations
  float* asv  = ws + o; o += (size_t)N * 4;
  float* adv  = ws + o; o += (size_t)N * 4;
  unsigned* deg       = (unsigned*)(ws + o); o += (size_t)N;
  unsigned* row_start = (unsigned*)(ws + o); o += (size_t)N;
  unsigned* cursor    = (unsigned*)(ws + o); o += (size_t)N;
  unsigned* bsum      = (unsigned*)(ws + o); o += 256;
  unsigned* boff      = (unsigned*)(ws + o); o += 256;
  unsigned* csr_src   = (unsigned*)(ws + o); o += (size_t)EE;

  const int egrid = (EE + 255) / 256;
  const int ngrid = (N + 3) / 4;
  const int ggrid = (N + 63) / 64;

  // ---- CSR build ----
  hipMemsetAsync(deg, 0, (size_t)N * sizeof(unsigned), stream);
  hist_kernel<<<egrid, 256, 0, stream>>>(ei, E, N, deg);
  partial_sum_kernel<<<256, 256, 0, stream>>>(deg, bsum, N, C);
  scan_bsum_kernel<<<1, 256, 0, stream>>>(bsum, boff);
  rowstart_kernel<<<256, 256, 0, stream>>>(deg, boff, row_start, cursor, N, C);
  scatter_kernel<<<egrid, 256, 0, stream>>>(ei, E, N, cursor, csr_src);

  // ---- layer 1 (K=256, H=4) ----
  gemm_fused_kernel<256,4><<<ggrid, 256, 0, stream>>>(x, W1, as1, ad1, h, asv, adv, N);
  aggregate_kernel<4><<<ngrid, 256, 0, stream>>>(row_start, deg, csr_src, h, asv, adv, b1, act1, N);

  // ---- layer 2 (K=128, H=1) ----
  gemm_fused_kernel<128,1><<<ggrid, 256, 0, stream>>>(act1, W2, as2, ad2, h, asv, adv, N);
  aggregate_kernel<1><<<ngrid, 256, 0, stream>>>(row_start, deg, csr_src, h, asv, adv, b2, out, N);
}

// Round 4
// 294.569 us; speedup vs baseline: 4.4167x; 1.1551x over previous
//
#include <hip/hip_runtime.h>
#include <hip/hip_fp16.h>

#define SLOPE_ATT 0.2f
#define SLOPE_ACT 0.01f

// ---------------------------------------------------------------------------
// Register-blocked fp32 GEMM (h = A @ B), A:[M][K], B:[K][128], fused att dots.
// Block 256 thr = 4 waves; C-tile 32 rows x 128 cols; per-thread 2x8.
// Grid ~1563 blocks -> ~6 blocks/CU for latency hiding via TLP.
// h output stored as fp16 (message matrix); att dots computed in fp32.
template<int K, int H>
__global__ __launch_bounds__(256)
void gemm_fused_kernel(const float* __restrict__ A, const float* __restrict__ B,
                       const float* __restrict__ att_s, const float* __restrict__ att_d,
                       __half* __restrict__ hout, float* __restrict__ a_src,
                       float* __restrict__ a_dst, int M)
{
  constexpr int BK = 16;
  constexpr int TILES = K / BK;
  __shared__ float As[BK][34];    // [k][row 0..31], pad 34
  __shared__ float Bs[BK][192];   // 16 col-chunks of 8 floats at stride 12 (2-way max)
  const int tid = threadIdx.x;
  const int tx = tid & 15;
  const int ty = tid >> 4;        // 0..15 -> rows ty*2..ty*2+1
  const int m0 = blockIdx.x * 32;

  // staging indices
  const int ar = tid >> 3;        // 0..31 (row)
  const int af = tid & 7;         // float2 idx along k
  const int bk = tid >> 5;        // 0..7 (k row; second pass +8)
  const int bc = tid & 31;        // col float4

  float acc[2][8];
#pragma unroll
  for (int i = 0; i < 2; ++i)
#pragma unroll
    for (int j = 0; j < 8; ++j) acc[i][j] = 0.f;

  const int gr = m0 + ar;
  float2 aReg; float4 bReg0, bReg1;
  aReg  = (gr < M) ? *(const float2*)&A[(size_t)gr * K + af * 2] : make_float2(0.f, 0.f);
  bReg0 = *(const float4*)&B[(size_t)bk * 128 + bc * 4];
  bReg1 = *(const float4*)&B[(size_t)(bk + 8) * 128 + bc * 4];

  for (int t = 0; t < TILES; ++t) {
    As[af*2+0][ar] = aReg.x;
    As[af*2+1][ar] = aReg.y;
    *(float4*)&Bs[bk    ][(bc >> 1) * 12 + (bc & 1) * 4] = bReg0;
    *(float4*)&Bs[bk + 8][(bc >> 1) * 12 + (bc & 1) * 4] = bReg1;
    __syncthreads();

    if (t + 1 < TILES) {
      const int kb = (t + 1) * BK;
      aReg  = (gr < M) ? *(const float2*)&A[(size_t)gr * K + kb + af * 2] : make_float2(0.f, 0.f);
      bReg0 = *(const float4*)&B[(size_t)(kb + bk) * 128 + bc * 4];
      bReg1 = *(const float4*)&B[(size_t)(kb + bk + 8) * 128 + bc * 4];
    }

#pragma unroll
    for (int k = 0; k < BK; ++k) {
      float2 av = *(const float2*)&As[k][ty * 2];
      float4 b0 = *(const float4*)&Bs[k][tx * 12];
      float4 b1 = *(const float4*)&Bs[k][tx * 12 + 4];
      float arr[2] = {av.x, av.y};
      float brr[8] = {b0.x, b0.y, b0.z, b0.w, b1.x, b1.y, b1.z, b1.w};
#pragma unroll
      for (int i = 0; i < 2; ++i)
#pragma unroll
        for (int j = 0; j < 8; ++j) acc[i][j] += arr[i] * brr[j];
    }
    __syncthreads();
  }

  // epilogue: store h (fp16) + fused attention dots (fp32)
  const float4 s0v = *(const float4*)&att_s[tx * 8];
  const float4 s1v = *(const float4*)&att_s[tx * 8 + 4];
  const float4 d0v = *(const float4*)&att_d[tx * 8];
  const float4 d1v = *(const float4*)&att_d[tx * 8 + 4];
#pragma unroll
  for (int i = 0; i < 2; ++i) {
    const int r = m0 + ty * 2 + i;
    const bool ok = r < M;
    if (ok) {
      union { __half2 h2[4]; float4 f4; } u;
      u.h2[0] = __floats2half2_rn(acc[i][0], acc[i][1]);
      u.h2[1] = __floats2half2_rn(acc[i][2], acc[i][3]);
      u.h2[2] = __floats2half2_rn(acc[i][4], acc[i][5]);
      u.h2[3] = __floats2half2_rn(acc[i][6], acc[i][7]);
      *(float4*)&hout[(size_t)r * 128 + tx * 8] = u.f4;
    }
    float sp = acc[i][0]*s0v.x + acc[i][1]*s0v.y + acc[i][2]*s0v.z + acc[i][3]*s0v.w
             + acc[i][4]*s1v.x + acc[i][5]*s1v.y + acc[i][6]*s1v.z + acc[i][7]*s1v.w;
    float dp = acc[i][0]*d0v.x + acc[i][1]*d0v.y + acc[i][2]*d0v.z + acc[i][3]*d0v.w
             + acc[i][4]*d1v.x + acc[i][5]*d1v.y + acc[i][6]*d1v.z + acc[i][7]*d1v.w;
    if (H == 4) {
      sp += __shfl_xor(sp, 1); sp += __shfl_xor(sp, 2);
      dp += __shfl_xor(dp, 1); dp += __shfl_xor(dp, 2);
      if ((tx & 3) == 0 && ok) {
        a_src[(size_t)r * 4 + (tx >> 2)] = sp;
        a_dst[(size_t)r * 4 + (tx >> 2)] = dp;
      }
    } else {
      sp += __shfl_xor(sp, 1); sp += __shfl_xor(sp, 2);
      sp += __shfl_xor(sp, 4); sp += __shfl_xor(sp, 8);
      dp += __shfl_xor(dp, 1); dp += __shfl_xor(dp, 2);
      dp += __shfl_xor(dp, 4); dp += __shfl_xor(dp, 8);
      if (tx == 0 && ok) { a_src[r] = sp; a_dst[r] = dp; }
    }
  }
}

// ---------------------------------------------------------------------------
// CSR construction (dst-sorted). Self-loops appended as edges [E, E+N).
__global__ __launch_bounds__(256)
void hist_kernel(const int* __restrict__ ei, int E, int N, unsigned* __restrict__ deg)
{
  int idx = blockIdx.x * blockDim.x + threadIdx.x;
  int EE = E + N;
  if (idx >= EE) return;
  int d = (idx < E) ? ei[E + idx] : (idx - E);
  atomicAdd(&deg[d], 1u);
}

__global__ __launch_bounds__(256)
void partial_sum_kernel(const unsigned* __restrict__ deg, unsigned* __restrict__ bsum,
                        int N, int C)
{
  __shared__ unsigned red[256];
  const int b = blockIdx.x;
  const int lo = b * C;
  const int hi = min(lo + C, N);
  unsigned s = 0;
  for (int i = lo + threadIdx.x; i < hi; i += 256) s += deg[i];
  red[threadIdx.x] = s;
  __syncthreads();
  for (int off = 128; off; off >>= 1) {
    if (threadIdx.x < off) red[threadIdx.x] += red[threadIdx.x + off];
    __syncthreads();
  }
  if (threadIdx.x == 0) bsum[b] = red[0];
}

__global__ __launch_bounds__(256)
void scan_bsum_kernel(const unsigned* __restrict__ bsum, unsigned* __restrict__ boff)
{
  __shared__ unsigned s[256];
  const int t = threadIdx.x;
  s[t] = bsum[t];
  __syncthreads();
  for (int off = 1; off < 256; off <<= 1) {
    unsigned v = (t >= off) ? s[t - off] : 0u;
    __syncthreads();
    s[t] += v;
    __syncthreads();
  }
  boff[t] = s[t] - bsum[t];   // exclusive
}

// C <= 256 assumed (N <= 65536).
__global__ __launch_bounds__(256)
void rowstart_kernel(const unsigned* __restrict__ deg, const unsigned* __restrict__ boff,
                     unsigned* __restrict__ row_start, unsigned* __restrict__ cursor,
                     int N, int C)
{
  __shared__ unsigned s[256];
  const int b = blockIdx.x;
  const int t = threadIdx.x;
  const int i = b * C + t;
  const unsigned d = (t < C && i < N) ? deg[i] : 0u;
  s[t] = d;
  __syncthreads();
  for (int off = 1; off < 256; off <<= 1) {
    unsigned v = (t >= off) ? s[t - off] : 0u;
    __syncthreads();
    s[t] += v;
    __syncthreads();
  }
  if (t < C && i < N) {
    unsigned rs = boff[b] + s[t] - d;
    row_start[i] = rs;
    cursor[i] = rs;
  }
}

__global__ __launch_bounds__(256)
void scatter_kernel(const int* __restrict__ ei, int E, int N,
                    unsigned* __restrict__ cursor, unsigned* __restrict__ csr_src)
{
  int idx = blockIdx.x * blockDim.x + threadIdx.x;
  int EE = E + N;
  if (idx >= EE) return;
  int s, d;
  if (idx < E) { s = ei[idx]; d = ei[E + idx]; } else { s = d = idx - E; }
  unsigned pos = atomicAdd(&cursor[d], 1u);
  csr_src[pos] = (unsigned)s;
}

// ---------------------------------------------------------------------------
// Fused per-node aggregation, softmax without max-subtraction (shift-invariant,
// |e| small). One wave per node; lane owns 2 features (half2 gather). Unroll-4
// to keep 4 independent gather chains in flight.
template<int H>
__global__ __launch_bounds__(256)
void aggregate_kernel(const unsigned* __restrict__ row_start,
                      const unsigned* __restrict__ deg,
                      const unsigned* __restrict__ csr_src,
                      const __half* __restrict__ h,
                      const float* __restrict__ a_src,
                      const float* __restrict__ a_dst,
                      const float* __restrict__ bias,
                      float* __restrict__ out, int N)
{
  const int n = blockIdx.x * 4 + (threadIdx.x >> 6);
  if (n >= N) return;
  const int l = threadIdx.x & 63;
  const int hd = (H == 4) ? (l >> 4) : 0;

  const float adn = a_dst[(size_t)n * H + hd];
  const unsigned beg = row_start[n];
  const unsigned cnt = deg[n];              // >= 1 (self loop)
  const __half2* __restrict__ h2 = (const __half2*)h;

  float Z = 0.f, ax = 0.f, ay = 0.f;
  unsigned i = 0;
  for (; i + 4 <= cnt; i += 4) {
    unsigned s0 = csr_src[beg + i];
    unsigned s1 = csr_src[beg + i + 1];
    unsigned s2 = csr_src[beg + i + 2];
    unsigned s3 = csr_src[beg + i + 3];
    float e0 = a_src[(size_t)s0 * H + hd] + adn;
    float e1 = a_src[(size_t)s1 * H + hd] + adn;
    float e2 = a_src[(size_t)s2 * H + hd] + adn;
    float e3 = a_src[(size_t)s3 * H + hd] + adn;
    float2 v0 = __half22float2(h2[(size_t)s0 * 64 + l]);
    float2 v1 = __half22float2(h2[(size_t)s1 * 64 + l]);
    float2 v2 = __half22float2(h2[(size_t)s2 * 64 + l]);
    float2 v3 = __half22float2(h2[(size_t)s3 * 64 + l]);
    e0 = (e0 >= 0.f) ? e0 : SLOPE_ATT * e0;
    e1 = (e1 >= 0.f) ? e1 : SLOPE_ATT * e1;
    e2 = (e2 >= 0.f) ? e2 : SLOPE_ATT * e2;
    e3 = (e3 >= 0.f) ? e3 : SLOPE_ATT * e3;
    float w0 = __expf(e0), w1 = __expf(e1), w2 = __expf(e2), w3 = __expf(e3);
    Z  += (w0 + w1) + (w2 + w3);
    ax += w0 * v0.x + w1 * v1.x + w2 * v2.x + w3 * v3.x;
    ay += w0 * v0.y + w1 * v1.y + w2 * v2.y + w3 * v3.y;
  }
  for (; i < cnt; ++i) {
    unsigned s0 = csr_src[beg + i];
    float e0 = a_src[(size_t)s0 * H + hd] + adn;
    e0 = (e0 >= 0.f) ? e0 : SLOPE_ATT * e0;
    float w0 = __expf(e0);
    float2 v0 = __half22float2(h2[(size_t)s0 * 64 + l]);
    Z  += w0;
    ax += w0 * v0.x;
    ay += w0 * v0.y;
  }
  const float inv = 1.f / (Z + 1e-16f);
  float2 b = ((const float2*)bias)[l];
  float ox = ax * inv + b.x;
  float oy = ay * inv + b.y;
  ox = (ox >= 0.f) ? ox : SLOPE_ACT * ox;
  oy = (oy >= 0.f) ? oy : SLOPE_ACT * oy;
  ((float2*)out)[(size_t)n * 64 + l] = make_float2(ox, oy);
}

// ---------------------------------------------------------------------------
extern "C" void kernel_launch(void* const* d_in, const int* in_sizes, int n_in,
                              void* d_out, int out_size, void* d_ws, size_t ws_size,
                              hipStream_t stream)
{
  const float* x   = (const float*)d_in[0];
  const int*   ei  = (const int*)d_in[1];
  const float* W1  = (const float*)d_in[2];
  const float* as1 = (const float*)d_in[3];
  const float* ad1 = (const float*)d_in[4];
  const float* b1  = (const float*)d_in[5];
  const float* W2  = (const float*)d_in[6];
  const float* as2 = (const float*)d_in[7];
  const float* ad2 = (const float*)d_in[8];
  const float* b2  = (const float*)d_in[9];
  float* out = (float*)d_out;

  const int N  = in_sizes[0] / 256;
  const int E  = in_sizes[1] / 2;
  const int EE = E + N;
  const int C  = (N + 255) / 256;   // <= 256 for N <= 65536

  float* ws = (float*)d_ws;
  size_t o = 0;
  __half* h  = (__half*)(ws + o); o += (size_t)N * 64;   // fp16 h, reused per layer
  float* act1 = ws + o; o += (size_t)N * 128;            // layer-1 activations (fp32)
  float* asv  = ws + o; o += (size_t)N * 4;
  float* adv  = ws + o; o += (size_t)N * 4;
  unsigned* deg       = (unsigned*)(ws + o); o += (size_t)N;
  unsigned* row_start = (unsigned*)(ws + o); o += (size_t)N;
  unsigned* cursor    = (unsigned*)(ws + o); o += (size_t)N;
  unsigned* bsum      = (unsigned*)(ws + o); o += 256;
  unsigned* boff      = (unsigned*)(ws + o); o += 256;
  unsigned* csr_src   = (unsigned*)(ws + o); o += (size_t)EE;

  const int egrid = (EE + 255) / 256;
  const int ngrid = (N + 3) / 4;
  const int ggrid = (N + 31) / 32;

  // ---- CSR build ----
  hipMemsetAsync(deg, 0, (size_t)N * sizeof(unsigned), stream);
  hist_kernel<<<egrid, 256, 0, stream>>>(ei, E, N, deg);
  partial_sum_kernel<<<256, 256, 0, stream>>>(deg, bsum, N, C);
  scan_bsum_kernel<<<1, 256, 0, stream>>>(bsum, boff);
  rowstart_kernel<<<256, 256, 0, stream>>>(deg, boff, row_start, cursor, N, C);
  scatter_kernel<<<egrid, 256, 0, stream>>>(ei, E, N, cursor, csr_src);

  // ---- layer 1 (K=256, H=4) ----
  gemm_fused_kernel<256,4><<<ggrid, 256, 0, stream>>>(x, W1, as1, ad1, h, asv, adv, N);
  aggregate_kernel<4><<<ngrid, 256, 0, stream>>>(row_start, deg, csr_src, h, asv, adv, b1, act1, N);

  // ---- layer 2 (K=128, H=1) ----
  gemm_fused_kernel<128,1><<<ggrid, 256, 0, stream>>>(act1, W2, as2, ad2, h, asv, adv, N);
  aggregate_kernel<1><<<ngrid, 256, 0, stream>>>(row_start, deg, csr_src, h, asv, adv, b2, out, N);
}

// Round 5
// 248.025 us; speedup vs baseline: 5.2455x; 1.1877x over previous
//
#include <hip/hip_runtime.h>
#include <hip/hip_fp16.h>

#define SLOPE_ATT 0.2f
#define SLOPE_ACT 0.01f

typedef _Float16 hf8 __attribute__((ext_vector_type(8)));
typedef float f32x4 __attribute__((ext_vector_type(4)));

// ---------------------------------------------------------------------------
// MFMA fp16 GEMM: h[M][128] = A[M][K] @ B[K][128], B pre-transposed fp16
// BT[128][K]. No LDS. One wave = 32 rows x 128 cols: acc[2 rowfrag][8 colfrag].
// Fragment layouts (v_mfma_f32_16x16x32_f16):
//   A: row = lane&15, k = (lane>>4)*8 + e   (8 consecutive k per lane)
//   B: col = lane&15, k = (lane>>4)*8 + e   (from BT row-major = col-major W)
//   D: col = lane&15, row = (lane>>4)*4 + reg   [m89-verified]
// Epilogue: h stored fp16 + fused att dots (16-lane shfl reduce).
template<int K, int H, bool A_FP32>
__global__ __launch_bounds__(256)
void gemm_mfma_kernel(const void* __restrict__ Av, const _Float16* __restrict__ BT,
                      const float* __restrict__ att_s, const float* __restrict__ att_d,
                      _Float16* __restrict__ hout, float* __restrict__ a_src,
                      float* __restrict__ a_dst, int M)
{
  const int lane = threadIdx.x & 63;
  const int wid  = threadIdx.x >> 6;
  const int li   = lane & 15;
  const int lk   = lane >> 4;
  const int rowbase = blockIdx.x * 128 + wid * 32;

  const float*    Af = (const float*)Av;
  const _Float16* Ah = (const _Float16*)Av;

  f32x4 acc[2][8];
#pragma unroll
  for (int i = 0; i < 2; ++i)
#pragma unroll
    for (int j = 0; j < 8; ++j) acc[i][j] = (f32x4){0.f, 0.f, 0.f, 0.f};

  const int r0 = min(rowbase + li,      M - 1);
  const int r1 = min(rowbase + 16 + li, M - 1);

#pragma unroll
  for (int ks = 0; ks < K / 32; ++ks) {
    const int kb = ks * 32 + lk * 8;
    hf8 a0, a1;
    if constexpr (A_FP32) {
      const float* p0 = &Af[(size_t)r0 * K + kb];
      const float* p1 = &Af[(size_t)r1 * K + kb];
      float4 x0a = *(const float4*)p0, x0b = *(const float4*)(p0 + 4);
      float4 x1a = *(const float4*)p1, x1b = *(const float4*)(p1 + 4);
      a0[0]=(_Float16)x0a.x; a0[1]=(_Float16)x0a.y; a0[2]=(_Float16)x0a.z; a0[3]=(_Float16)x0a.w;
      a0[4]=(_Float16)x0b.x; a0[5]=(_Float16)x0b.y; a0[6]=(_Float16)x0b.z; a0[7]=(_Float16)x0b.w;
      a1[0]=(_Float16)x1a.x; a1[1]=(_Float16)x1a.y; a1[2]=(_Float16)x1a.z; a1[3]=(_Float16)x1a.w;
      a1[4]=(_Float16)x1b.x; a1[5]=(_Float16)x1b.y; a1[6]=(_Float16)x1b.z; a1[7]=(_Float16)x1b.w;
    } else {
      a0 = *(const hf8*)&Ah[(size_t)r0 * K + kb];
      a1 = *(const hf8*)&Ah[(size_t)r1 * K + kb];
    }
#pragma unroll
    for (int cf = 0; cf < 8; ++cf) {
      hf8 b = *(const hf8*)&BT[(size_t)(cf * 16 + li) * K + kb];
      acc[0][cf] = __builtin_amdgcn_mfma_f32_16x16x32_f16(a0, b, acc[0][cf], 0, 0, 0);
      acc[1][cf] = __builtin_amdgcn_mfma_f32_16x16x32_f16(a1, b, acc[1][cf], 0, 0, 0);
    }
  }

  // epilogue
  float sA[8], dA[8];
#pragma unroll
  for (int cf = 0; cf < 8; ++cf) {
    sA[cf] = att_s[cf * 16 + li];
    dA[cf] = att_d[cf * 16 + li];
  }

  const bool full = (rowbase + 32) <= M;
#pragma unroll
  for (int rf = 0; rf < 2; ++rf) {
    const int rb = rowbase + rf * 16 + lk * 4;
    // h stores (fp16, scattered shorts; wave fills full lines over the sequence)
#pragma unroll
    for (int reg = 0; reg < 4; ++reg) {
      const int r = rb + reg;
      if (full || r < M) {
#pragma unroll
        for (int cf = 0; cf < 8; ++cf)
          hout[(size_t)r * 128 + cf * 16 + li] = (_Float16)acc[rf][cf][reg];
      }
    }
    // fused attention dots
    if constexpr (H == 4) {
#pragma unroll
      for (int hh = 0; hh < 4; ++hh) {
#pragma unroll
        for (int reg = 0; reg < 4; ++reg) {
          float sp = acc[rf][2*hh][reg] * sA[2*hh] + acc[rf][2*hh+1][reg] * sA[2*hh+1];
          float dp = acc[rf][2*hh][reg] * dA[2*hh] + acc[rf][2*hh+1][reg] * dA[2*hh+1];
          sp += __shfl_xor(sp, 1); sp += __shfl_xor(sp, 2);
          sp += __shfl_xor(sp, 4); sp += __shfl_xor(sp, 8);
          dp += __shfl_xor(dp, 1); dp += __shfl_xor(dp, 2);
          dp += __shfl_xor(dp, 4); dp += __shfl_xor(dp, 8);
          const int r = rb + reg;
          if (li == 0 && r < M) {
            a_src[(size_t)r * 4 + hh] = sp;
            a_dst[(size_t)r * 4 + hh] = dp;
          }
        }
      }
    } else {
#pragma unroll
      for (int reg = 0; reg < 4; ++reg) {
        float sp = 0.f, dp = 0.f;
#pragma unroll
        for (int cf = 0; cf < 8; ++cf) {
          sp += acc[rf][cf][reg] * sA[cf];
          dp += acc[rf][cf][reg] * dA[cf];
        }
        sp += __shfl_xor(sp, 1); sp += __shfl_xor(sp, 2);
        sp += __shfl_xor(sp, 4); sp += __shfl_xor(sp, 8);
        dp += __shfl_xor(dp, 1); dp += __shfl_xor(dp, 2);
        dp += __shfl_xor(dp, 4); dp += __shfl_xor(dp, 8);
        const int r = rb + reg;
        if (li == 0 && r < M) { a_src[r] = sp; a_dst[r] = dp; }
      }
    }
  }
}

// W [K][128] fp32 -> WT [128][K] fp16 (tiny)
__global__ __launch_bounds__(256)
void convW_kernel(const float* __restrict__ W, _Float16* __restrict__ WT, int K)
{
  int idx = blockIdx.x * 256 + threadIdx.x;
  if (idx >= K * 128) return;
  int k = idx >> 7, c = idx & 127;
  WT[(size_t)c * K + k] = (_Float16)W[idx];
}

// ---------------------------------------------------------------------------
// CSR construction (dst-sorted). Self-loops appended as edges [E, E+N).
__global__ __launch_bounds__(256)
void hist_kernel(const int* __restrict__ ei, int E, int N, unsigned* __restrict__ deg)
{
  int idx = blockIdx.x * blockDim.x + threadIdx.x;
  int EE = E + N;
  if (idx >= EE) return;
  int d = (idx < E) ? ei[E + idx] : (idx - E);
  atomicAdd(&deg[d], 1u);
}

__global__ __launch_bounds__(256)
void partial_sum_kernel(const unsigned* __restrict__ deg, unsigned* __restrict__ bsum,
                        int N, int C)
{
  __shared__ unsigned red[256];
  const int b = blockIdx.x;
  const int lo = b * C;
  const int hi = min(lo + C, N);
  unsigned s = 0;
  for (int i = lo + threadIdx.x; i < hi; i += 256) s += deg[i];
  red[threadIdx.x] = s;
  __syncthreads();
  for (int off = 128; off; off >>= 1) {
    if (threadIdx.x < off) red[threadIdx.x] += red[threadIdx.x + off];
    __syncthreads();
  }
  if (threadIdx.x == 0) bsum[b] = red[0];
}

__global__ __launch_bounds__(256)
void scan_bsum_kernel(const unsigned* __restrict__ bsum, unsigned* __restrict__ boff)
{
  __shared__ unsigned s[256];
  const int t = threadIdx.x;
  s[t] = bsum[t];
  __syncthreads();
  for (int off = 1; off < 256; off <<= 1) {
    unsigned v = (t >= off) ? s[t - off] : 0u;
    __syncthreads();
    s[t] += v;
    __syncthreads();
  }
  boff[t] = s[t] - bsum[t];   // exclusive
}

// C <= 256 assumed (N <= 65536).
__global__ __launch_bounds__(256)
void rowstart_kernel(const unsigned* __restrict__ deg, const unsigned* __restrict__ boff,
                     unsigned* __restrict__ row_start, unsigned* __restrict__ cursor,
                     int N, int C)
{
  __shared__ unsigned s[256];
  const int b = blockIdx.x;
  const int t = threadIdx.x;
  const int i = b * C + t;
  const unsigned d = (t < C && i < N) ? deg[i] : 0u;
  s[t] = d;
  __syncthreads();
  for (int off = 1; off < 256; off <<= 1) {
    unsigned v = (t >= off) ? s[t - off] : 0u;
    __syncthreads();
    s[t] += v;
    __syncthreads();
  }
  if (t < C && i < N) {
    unsigned rs = boff[b] + s[t] - d;
    row_start[i] = rs;
    cursor[i] = rs;
  }
}

__global__ __launch_bounds__(256)
void scatter_kernel(const int* __restrict__ ei, int E, int N,
                    unsigned* __restrict__ cursor, unsigned* __restrict__ csr_src)
{
  int idx = blockIdx.x * blockDim.x + threadIdx.x;
  int EE = E + N;
  if (idx >= EE) return;
  int s, d;
  if (idx < E) { s = ei[idx]; d = ei[E + idx]; } else { s = d = idx - E; }
  unsigned pos = atomicAdd(&cursor[d], 1u);
  csr_src[pos] = (unsigned)s;
}

// ---------------------------------------------------------------------------
// Fused per-node aggregation, softmax without max-subtraction (shift-invariant,
// |e| small). One wave per node; lane owns 2 features (half2 gather). Unroll-4.
// OUT_HALF: write act1 as fp16 (feeds gemm2 A directly); else fp32 (d_out).
template<int H, bool OUT_HALF>
__global__ __launch_bounds__(256)
void aggregate_kernel(const unsigned* __restrict__ row_start,
                      const unsigned* __restrict__ deg,
                      const unsigned* __restrict__ csr_src,
                      const __half* __restrict__ h,
                      const float* __restrict__ a_src,
                      const float* __restrict__ a_dst,
                      const float* __restrict__ bias,
                      void* __restrict__ outv, int N)
{
  const int n = blockIdx.x * 4 + (threadIdx.x >> 6);
  if (n >= N) return;
  const int l = threadIdx.x & 63;
  const int hd = (H == 4) ? (l >> 4) : 0;

  const float adn = a_dst[(size_t)n * H + hd];
  const unsigned beg = row_start[n];
  const unsigned cnt = deg[n];              // >= 1 (self loop)
  const __half2* __restrict__ h2 = (const __half2*)h;

  float Z = 0.f, ax = 0.f, ay = 0.f;
  unsigned i = 0;
  for (; i + 4 <= cnt; i += 4) {
    unsigned s0 = csr_src[beg + i];
    unsigned s1 = csr_src[beg + i + 1];
    unsigned s2 = csr_src[beg + i + 2];
    unsigned s3 = csr_src[beg + i + 3];
    float e0 = a_src[(size_t)s0 * H + hd] + adn;
    float e1 = a_src[(size_t)s1 * H + hd] + adn;
    float e2 = a_src[(size_t)s2 * H + hd] + adn;
    float e3 = a_src[(size_t)s3 * H + hd] + adn;
    float2 v0 = __half22float2(h2[(size_t)s0 * 64 + l]);
    float2 v1 = __half22float2(h2[(size_t)s1 * 64 + l]);
    float2 v2 = __half22float2(h2[(size_t)s2 * 64 + l]);
    float2 v3 = __half22float2(h2[(size_t)s3 * 64 + l]);
    e0 = (e0 >= 0.f) ? e0 : SLOPE_ATT * e0;
    e1 = (e1 >= 0.f) ? e1 : SLOPE_ATT * e1;
    e2 = (e2 >= 0.f) ? e2 : SLOPE_ATT * e2;
    e3 = (e3 >= 0.f) ? e3 : SLOPE_ATT * e3;
    float w0 = __expf(e0), w1 = __expf(e1), w2 = __expf(e2), w3 = __expf(e3);
    Z  += (w0 + w1) + (w2 + w3);
    ax += w0 * v0.x + w1 * v1.x + w2 * v2.x + w3 * v3.x;
    ay += w0 * v0.y + w1 * v1.y + w2 * v2.y + w3 * v3.y;
  }
  for (; i < cnt; ++i) {
    unsigned s0 = csr_src[beg + i];
    float e0 = a_src[(size_t)s0 * H + hd] + adn;
    e0 = (e0 >= 0.f) ? e0 : SLOPE_ATT * e0;
    float w0 = __expf(e0);
    float2 v0 = __half22float2(h2[(size_t)s0 * 64 + l]);
    Z  += w0;
    ax += w0 * v0.x;
    ay += w0 * v0.y;
  }
  const float inv = 1.f / (Z + 1e-16f);
  float2 b = ((const float2*)bias)[l];
  float ox = ax * inv + b.x;
  float oy = ay * inv + b.y;
  ox = (ox >= 0.f) ? ox : SLOPE_ACT * ox;
  oy = (oy >= 0.f) ? oy : SLOPE_ACT * oy;
  if constexpr (OUT_HALF)
    ((__half2*)outv)[(size_t)n * 64 + l] = __floats2half2_rn(ox, oy);
  else
    ((float2*)outv)[(size_t)n * 64 + l] = make_float2(ox, oy);
}

// ---------------------------------------------------------------------------
extern "C" void kernel_launch(void* const* d_in, const int* in_sizes, int n_in,
                              void* d_out, int out_size, void* d_ws, size_t ws_size,
                              hipStream_t stream)
{
  const float* x   = (const float*)d_in[0];
  const int*   ei  = (const int*)d_in[1];
  const float* W1  = (const float*)d_in[2];
  const float* as1 = (const float*)d_in[3];
  const float* ad1 = (const float*)d_in[4];
  const float* b1  = (const float*)d_in[5];
  const float* W2  = (const float*)d_in[6];
  const float* as2 = (const float*)d_in[7];
  const float* ad2 = (const float*)d_in[8];
  const float* b2  = (const float*)d_in[9];
  float* out = (float*)d_out;

  const int N  = in_sizes[0] / 256;
  const int E  = in_sizes[1] / 2;
  const int EE = E + N;
  const int C  = (N + 255) / 256;   // <= 256 for N <= 65536

  float* ws = (float*)d_ws;
  size_t o = 0;
  _Float16* h    = (_Float16*)(ws + o); o += (size_t)N * 64;   // [N][128] fp16
  _Float16* act1 = (_Float16*)(ws + o); o += (size_t)N * 64;   // [N][128] fp16
  float* asv = ws + o; o += (size_t)N * 4;
  float* adv = ws + o; o += (size_t)N * 4;
  _Float16* W1T = (_Float16*)(ws + o); o += 128 * 256 / 2;     // [128][256] fp16
  _Float16* W2T = (_Float16*)(ws + o); o += 128 * 128 / 2;     // [128][128] fp16
  unsigned* deg       = (unsigned*)(ws + o); o += (size_t)N;
  unsigned* row_start = (unsigned*)(ws + o); o += (size_t)N;
  unsigned* cursor    = (unsigned*)(ws + o); o += (size_t)N;
  unsigned* bsum      = (unsigned*)(ws + o); o += 256;
  unsigned* boff      = (unsigned*)(ws + o); o += 256;
  unsigned* csr_src   = (unsigned*)(ws + o); o += (size_t)EE;

  const int egrid = (EE + 255) / 256;
  const int ngrid = (N + 3) / 4;
  const int ggrid = (N + 127) / 128;

  // ---- weight transpose+fp16 (tiny) ----
  convW_kernel<<<(256 * 128 + 255) / 256, 256, 0, stream>>>(W1, W1T, 256);
  convW_kernel<<<(128 * 128 + 255) / 256, 256, 0, stream>>>(W2, W2T, 128);

  // ---- CSR build ----
  hipMemsetAsync(deg, 0, (size_t)N * sizeof(unsigned), stream);
  hist_kernel<<<egrid, 256, 0, stream>>>(ei, E, N, deg);
  partial_sum_kernel<<<256, 256, 0, stream>>>(deg, bsum, N, C);
  scan_bsum_kernel<<<1, 256, 0, stream>>>(bsum, boff);
  rowstart_kernel<<<256, 256, 0, stream>>>(deg, boff, row_start, cursor, N, C);
  scatter_kernel<<<egrid, 256, 0, stream>>>(ei, E, N, cursor, csr_src);

  // ---- layer 1 (K=256, H=4): A = x fp32 ----
  gemm_mfma_kernel<256, 4, true><<<ggrid, 256, 0, stream>>>(
      x, W1T, as1, ad1, h, asv, adv, N);
  aggregate_kernel<4, true><<<ngrid, 256, 0, stream>>>(
      row_start, deg, csr_src, (const __half*)h, asv, adv, b1, act1, N);

  // ---- layer 2 (K=128, H=1): A = act1 fp16 ----
  gemm_mfma_kernel<128, 1, false><<<ggrid, 256, 0, stream>>>(
      act1, W2T, as2, ad2, h, asv, adv, N);
  aggregate_kernel<1, false><<<ngrid, 256, 0, stream>>>(
      row_start, deg, csr_src, (const __half*)h, asv, adv, b2, out, N);
}